// Round 1
// baseline (316.951 us; speedup 1.0000x reference)
//
#include <hip/hip_runtime.h>
#include <stdint.h>

typedef unsigned short u16;
typedef __attribute__((ext_vector_type(4))) float f32x4;
typedef __attribute__((ext_vector_type(8))) short bf16x8;
typedef __attribute__((ext_vector_type(4))) short bf16x4;
typedef __attribute__((ext_vector_type(4))) int i32x4;

// fp32 -> bf16 round-to-nearest-even
__device__ inline u16 f2b(float x) {
  union { float f; uint32_t u; } t; t.f = x;
  uint32_t r = t.u + 0x7FFFu + ((t.u >> 16) & 1u);
  return (u16)(r >> 16);
}

// ---------------- kernel 1: hidden_states fp32 -> bf16 ----------------
__global__ void cvt_hs_k(const float* __restrict__ in, u16* __restrict__ outp, int n) {
  int i = (blockIdx.x * 256 + threadIdx.x) * 4;
  if (i >= n) return;
  float4 v = *(const float4*)(in + i);
  ushort4 o = { f2b(v.x), f2b(v.y), f2b(v.z), f2b(v.w) };
  *(ushort4*)(outp + i) = o;
}

// ---------------- kernel 2: W [k][n] fp32 -> Wt [n][k] bf16 (x3) ----------------
__global__ void twk(const float* __restrict__ Wq, const float* __restrict__ Wk,
                    const float* __restrict__ Wv, u16* __restrict__ Wt) {
  __shared__ float tile[64][65];
  const float* W = (blockIdx.z == 0) ? Wq : ((blockIdx.z == 1) ? Wk : Wv);
  int n0 = blockIdx.x * 64, k0 = blockIdx.y * 64;
  int tid = threadIdx.x;
#pragma unroll 4
  for (int i = 0; i < 16; ++i) {
    int idx = i * 256 + tid; int r = idx >> 6, c = idx & 63;
    tile[r][c] = W[(k0 + r) * 1024 + n0 + c];
  }
  __syncthreads();
  u16* dst = Wt + blockIdx.z * 1048576;
#pragma unroll 4
  for (int i = 0; i < 16; ++i) {
    int idx = i * 256 + tid; int r = idx >> 6, c = idx & 63;
    dst[(n0 + r) * 1024 + k0 + c] = f2b(tile[c][r]);
  }
}

// ---------------- kernel 3: QKV GEMM ----------------
// hsb [8192][1024] bf16 ; wt [3][1024][1024] bf16 (n-major, i.e. W^T)
// outputs: Q,K as [B][H][S][64] bf16 ; Vt as [B][H][64][S] bf16
// D = T1 . T2^T where T1,T2 tiles are [128 rows][64 k] in swizzled LDS.
// Q/K blocks: T1=Wt, T2=hs  -> D[n][m]  (lane regs contiguous in d) -> packed stores
// V  blocks:  T1=hs, T2=Wt  -> D[m][n]  (lane regs contiguous in s) -> Vt stores
__global__ __launch_bounds__(256) void qkv_gemm_k(
    const u16* __restrict__ hsb, const u16* __restrict__ wt,
    const float* __restrict__ bq, const float* __restrict__ bk, const float* __restrict__ bv,
    u16* __restrict__ Qo, u16* __restrict__ Ko, u16* __restrict__ Vto) {
  __shared__ u16 t1[128 * 64];
  __shared__ u16 t2[128 * 64];
  const int tid = threadIdx.x;
  const int w = tid >> 6, l = tid & 63, g = l >> 4, lm = l & 15;
  const int nbase = blockIdx.x * 128;       // 0..3071 over {q,k,v}
  const int wi = nbase >> 10;               // 0=q 1=k 2=v
  const int nloc0 = nbase & 1023;
  const int mbase = blockIdx.y * 128;
  const bool swapped = (wi < 2);
  const u16* T1g = swapped ? (wt + wi * 1048576 + nloc0 * 1024) : (hsb + mbase * 1024);
  const u16* T2g = swapped ? (hsb + mbase * 1024) : (wt + 2 * 1048576 + nloc0 * 1024);

  f32x4 acc[4][4];
#pragma unroll
  for (int i = 0; i < 4; ++i)
#pragma unroll
    for (int j = 0; j < 4; ++j)
#pragma unroll
      for (int r = 0; r < 4; ++r) acc[i][j][r] = 0.f;

  const int r1w = (w >> 1) * 64;
  const int r2w = (w & 1) * 64;

  for (int kb = 0; kb < 1024; kb += 64) {
    __syncthreads();
#pragma unroll
    for (int p = 0; p < 4; ++p) {
      int idx = p * 256 + tid;
      int r = idx >> 3, c = idx & 7;
      int sc = ((c ^ (r & 7)) * 8);
      *(i32x4*)(t1 + r * 64 + sc) = *(const i32x4*)(T1g + r * 1024 + kb + c * 8);
      *(i32x4*)(t2 + r * 64 + sc) = *(const i32x4*)(T2g + r * 1024 + kb + c * 8);
    }
    __syncthreads();
#pragma unroll
    for (int ks = 0; ks < 2; ++ks) {
      bf16x8 fa[4], fb[4];
#pragma unroll
      for (int i = 0; i < 4; ++i) {
        int ra = r1w + i * 16 + lm;
        fa[i] = *(const bf16x8*)(t1 + ra * 64 + (((g + 4 * ks) ^ (ra & 7)) * 8));
        int rb = r2w + i * 16 + lm;
        fb[i] = *(const bf16x8*)(t2 + rb * 64 + (((g + 4 * ks) ^ (rb & 7)) * 8));
      }
#pragma unroll
      for (int i = 0; i < 4; ++i)
#pragma unroll
        for (int j = 0; j < 4; ++j)
          acc[i][j] = __builtin_amdgcn_mfma_f32_16x16x32_bf16(fa[i], fb[j], acc[i][j], 0, 0, 0);
    }
  }

  if (swapped) {
    u16* O = (wi == 0) ? Qo : Ko;
    const float* bias = (wi == 0) ? bq : bk;
#pragma unroll
    for (int i = 0; i < 4; ++i) {
      int nl = nloc0 + r1w + i * 16 + g * 4;   // 4 consecutive n = d
      f32x4 bv4 = *(const f32x4*)(bias + nl);
      int d = nl & 63, h = nl >> 6;
#pragma unroll
      for (int j = 0; j < 4; ++j) {
        int m = mbase + r2w + j * 16 + lm;
        int bb = m >> 11, s = m & 2047;
        f32x4 v = acc[i][j];
        ushort4 o = { f2b(v[0] + bv4[0]), f2b(v[1] + bv4[1]),
                      f2b(v[2] + bv4[2]), f2b(v[3] + bv4[3]) };
        *(ushort4*)(O + ((size_t)(bb * 16 + h) * 2048 + s) * 64 + d) = o;
      }
    }
  } else {
#pragma unroll
    for (int j = 0; j < 4; ++j) {
      int nl = nloc0 + r2w + j * 16 + lm;
      float bias = bv[nl];
      int d = nl & 63, h = nl >> 6;
#pragma unroll
      for (int i = 0; i < 4; ++i) {
        int m = mbase + r1w + i * 16 + g * 4;  // 4 consecutive m = s
        int bb = m >> 11, s = m & 2047;
        f32x4 v = acc[i][j];
        ushort4 o = { f2b(v[0] + bias), f2b(v[1] + bias),
                      f2b(v[2] + bias), f2b(v[3] + bias) };
        *(ushort4*)(Vto + ((size_t)(bb * 16 + h) * 64 + d) * 2048 + s) = o;
      }
    }
  }
}

// ---------------- kernel 4: flash attention ----------------
// grid (S/64, B*H), 4 waves x 16 q-rows. Swapped QK^T: St[sk][sq]=mfma(Kfrag,Qfrag)
// PV: two 16-sk P tiles fused into one 16x16x32 mfma via shared k-index bijection.
__global__ __launch_bounds__(256) void attn_k(
    const u16* __restrict__ Qg, const u16* __restrict__ Kg, const u16* __restrict__ Vtg,
    const float* __restrict__ maskg, float* __restrict__ outp) {
  __shared__ u16 kt[128 * 64];   // [sk 128][d 64] swizzled
  __shared__ u16 vt[64 * 128];   // [d 64][sk 128] swizzled
  __shared__ float mk[128];
  const int tid = threadIdx.x;
  const int w = tid >> 6, l = tid & 63, g = l >> 4, lm = l & 15;
  const int bh = blockIdx.y, b = bh >> 4, h = bh & 15;
  const int q0 = blockIdx.x * 64 + w * 16;
  const u16* Qb = Qg + ((size_t)bh * 2048 + q0) * 64;
  const u16* Kb = Kg + (size_t)bh * 2048 * 64;
  const u16* Vb = Vtg + (size_t)bh * 64 * 2048;
  const float* mb = maskg + b * 2048;

  bf16x8 qf0 = *(const bf16x8*)(Qb + lm * 64 + g * 8);
  bf16x8 qf1 = *(const bf16x8*)(Qb + lm * 64 + 32 + g * 8);

  f32x4 ctx[4];
#pragma unroll
  for (int dt = 0; dt < 4; ++dt)
#pragma unroll
    for (int r = 0; r < 4; ++r) ctx[dt][r] = 0.f;
  float mrun = -3.0e38f, lrun = 0.f;

  for (int kv = 0; kv < 2048; kv += 128) {
    __syncthreads();
#pragma unroll
    for (int p = 0; p < 4; ++p) {
      int idx = p * 256 + tid;
      { int r = idx >> 3, c = idx & 7;     // K tile: 128 rows x 64
        *(i32x4*)(kt + r * 64 + ((c ^ (r & 7)) * 8)) =
            *(const i32x4*)(Kb + (size_t)(kv + r) * 64 + c * 8); }
      { int r = idx >> 4, c = idx & 15;    // Vt tile: 64 rows x 128
        *(i32x4*)(vt + r * 128 + ((c ^ (r & 7)) * 8)) =
            *(const i32x4*)(Vb + (size_t)r * 2048 + kv + c * 8); }
    }
    if (tid < 128) mk[tid] = mb[kv + tid];
    __syncthreads();

    f32x4 st[8];
#pragma unroll
    for (int t = 0; t < 8; ++t)
#pragma unroll
      for (int r = 0; r < 4; ++r) st[t][r] = 0.f;

#pragma unroll
    for (int ks = 0; ks < 2; ++ks) {
      bf16x8 qf = ks ? qf1 : qf0;
#pragma unroll
      for (int t = 0; t < 8; ++t) {
        int r = t * 16 + lm;
        bf16x8 kf = *(const bf16x8*)(kt + r * 64 + (((g + 4 * ks) ^ (r & 7)) * 8));
        st[t] = __builtin_amdgcn_mfma_f32_16x16x32_bf16(kf, qf, st[t], 0, 0, 0);
      }
    }

    float tmax = -3.0e38f;
#pragma unroll
    for (int t = 0; t < 8; ++t) {
      f32x4 mv = *(const f32x4*)(mk + t * 16 + g * 4);
#pragma unroll
      for (int r = 0; r < 4; ++r) {
        float s = st[t][r] * 0.125f + mv[r];
        st[t][r] = s;
        tmax = fmaxf(tmax, s);
      }
    }
    tmax = fmaxf(tmax, __shfl_xor(tmax, 16));
    tmax = fmaxf(tmax, __shfl_xor(tmax, 32));
    float mnew = fmaxf(mrun, tmax);
    float corr = __expf(mrun - mnew);   // first tile: exp(-inf)=0
    float lsum = 0.f;
    bf16x4 pt[8];
#pragma unroll
    for (int t = 0; t < 8; ++t)
#pragma unroll
      for (int r = 0; r < 4; ++r) {
        float p = __expf(st[t][r] - mnew);
        lsum += p;
        pt[t][r] = (short)f2b(p);
      }
    lsum += __shfl_xor(lsum, 16);
    lsum += __shfl_xor(lsum, 32);
    lrun = lrun * corr + lsum;
    mrun = mnew;
#pragma unroll
    for (int dt = 0; dt < 4; ++dt)
#pragma unroll
      for (int r = 0; r < 4; ++r) ctx[dt][r] *= corr;

    // PV: fuse tile pair (t0,t1) into one K=32 mfma (same k->sk bijection on A and B)
#pragma unroll
    for (int tp = 0; tp < 4; ++tp) {
      int t0 = 2 * tp, t1 = 2 * tp + 1;
      bf16x8 pb;
#pragma unroll
      for (int i = 0; i < 4; ++i) { pb[i] = pt[t0][i]; pb[4 + i] = pt[t1][i]; }
#pragma unroll
      for (int dt = 0; dt < 4; ++dt) {
        int r = dt * 16 + lm;
        int base = r * 128;
        bf16x4 v0 = *(const bf16x4*)(vt + base + (((2 * t0 + (g >> 1)) ^ (r & 7)) * 8) + (g & 1) * 4);
        bf16x4 v1 = *(const bf16x4*)(vt + base + (((2 * t1 + (g >> 1)) ^ (r & 7)) * 8) + (g & 1) * 4);
        bf16x8 va;
#pragma unroll
        for (int i = 0; i < 4; ++i) { va[i] = v0[i]; va[4 + i] = v1[i]; }
        ctx[dt] = __builtin_amdgcn_mfma_f32_16x16x32_bf16(va, pb, ctx[dt], 0, 0, 0);
      }
    }
  }

  float inv = 1.f / lrun;
  int sq = q0 + lm;
  float* ob = outp + ((size_t)(b * 2048 + sq)) * 1024 + h * 64;
#pragma unroll
  for (int dt = 0; dt < 4; ++dt) {
    f32x4 o;
#pragma unroll
    for (int r = 0; r < 4; ++r) o[r] = ctx[dt][r] * inv;
    *(f32x4*)(ob + dt * 16 + g * 4) = o;
  }
}

extern "C" void kernel_launch(void* const* d_in, const int* in_sizes, int n_in,
                              void* d_out, int out_size, void* d_ws, size_t ws_size,
                              hipStream_t stream) {
  const float* hs   = (const float*)d_in[0];
  const float* mask = (const float*)d_in[1];
  const float* Wq   = (const float*)d_in[2];
  const float* bq   = (const float*)d_in[3];
  const float* Wk   = (const float*)d_in[4];
  const float* bk   = (const float*)d_in[5];
  const float* Wv   = (const float*)d_in[6];
  const float* bv   = (const float*)d_in[7];
  float* out = (float*)d_out;

  // workspace layout (needs 72 MB)
  char* ws = (char*)d_ws;
  u16* hsb = (u16*)(ws);                          // 16 MB: hs bf16 [8192][1024]
  u16* wt  = (u16*)(ws + (16u << 20));            //  6 MB: Wt bf16 [3][1024][1024]
  u16* Qb  = (u16*)(ws + (24u << 20));            // 16 MB: Q  [B][H][S][64]
  u16* Kb  = (u16*)(ws + (40u << 20));            // 16 MB: K  [B][H][S][64]
  u16* Vtb = (u16*)(ws + (56u << 20));            // 16 MB: Vt [B][H][64][S]

  cvt_hs_k<<<dim3(8192), dim3(256), 0, stream>>>(hs, hsb, 8388608);
  twk<<<dim3(16, 16, 3), dim3(256), 0, stream>>>(Wq, Wk, Wv, wt);
  qkv_gemm_k<<<dim3(24, 64), dim3(256), 0, stream>>>(hsb, wt, bq, bk, bv, Qb, Kb, Vtb);
  attn_k<<<dim3(32, 64), dim3(256), 0, stream>>>(Qb, Kb, Vtb, mask, out);
}

// Round 2
// 267.637 us; speedup vs baseline: 1.1843x; 1.1843x over previous
//
#include <hip/hip_runtime.h>
#include <stdint.h>

typedef unsigned short u16;
typedef __attribute__((ext_vector_type(4))) float f32x4;
typedef __attribute__((ext_vector_type(8))) short bf16x8;
typedef __attribute__((ext_vector_type(4))) int i32x4;

#define LOG2E 1.4426950408889634f

// fp32 -> bf16 round-to-nearest-even
__device__ inline u16 f2b(float x) {
  union { float f; uint32_t u; } t; t.f = x;
  uint32_t r = t.u + 0x7FFFu + ((t.u >> 16) & 1u);
  return (u16)(r >> 16);
}

// packed fp32 pair -> bf16 pair (1 VALU op)
__device__ inline int cvtpk(float a, float b) {
  int r;
  asm("v_cvt_pk_bf16_f32 %0, %1, %2" : "=v"(r) : "v"(a), "v"(b));
  return r;
}

// 2^x via v_exp_f32
__device__ inline float exp2a(float x) {
  float r;
  asm("v_exp_f32 %0, %1" : "=v"(r) : "v"(x));
  return r;
}

// async global->LDS 16B (DMA, no VGPR round-trip). LDS dest must be linear
// (wave-uniform base + lane*16); swizzle goes on the GLOBAL source address.
typedef const __attribute__((address_space(1))) void* gas_t;
typedef __attribute__((address_space(3))) void* las_t;
__device__ inline void gld16(const void* g, void* l) {
  __builtin_amdgcn_global_load_lds((gas_t)g, (las_t)l, 16, 0, 0);
}

// ---------------- kernel 1: hidden_states fp32 -> bf16 ----------------
__global__ void cvt_hs_k(const float* __restrict__ in, u16* __restrict__ outp, int n) {
  int i = (blockIdx.x * 256 + threadIdx.x) * 4;
  if (i >= n) return;
  float4 v = *(const float4*)(in + i);
  ushort4 o = { f2b(v.x), f2b(v.y), f2b(v.z), f2b(v.w) };
  *(ushort4*)(outp + i) = o;
}

// ---------------- kernel 2: W [k][n] fp32 -> Wt [n][k] bf16 (x3) ----------------
__global__ void twk(const float* __restrict__ Wq, const float* __restrict__ Wk,
                    const float* __restrict__ Wv, u16* __restrict__ Wt) {
  __shared__ float tile[64][65];
  const float* W = (blockIdx.z == 0) ? Wq : ((blockIdx.z == 1) ? Wk : Wv);
  int n0 = blockIdx.x * 64, k0 = blockIdx.y * 64;
  int tid = threadIdx.x;
#pragma unroll 4
  for (int i = 0; i < 16; ++i) {
    int idx = i * 256 + tid; int r = idx >> 6, c = idx & 63;
    tile[r][c] = W[(k0 + r) * 1024 + n0 + c];
  }
  __syncthreads();
  u16* dst = Wt + blockIdx.z * 1048576;
#pragma unroll 4
  for (int i = 0; i < 16; ++i) {
    int idx = i * 256 + tid; int r = idx >> 6, c = idx & 63;
    dst[(n0 + r) * 1024 + k0 + c] = f2b(tile[c][r]);
  }
}

// ---------------- kernel 3: QKV GEMM ----------------
// global_load_lds staging, source-side XOR swizzle, LDS linear.
// LDS(r, chunk c) = global(r, chunk c^(r&7)); read global chunk x at c = x^(r&7).
// Q/K: D[n][m] (regs contiguous in d) -> [B][H][S][64].
// V:   D[m][n] -> Vt_perm [B][H][64][2048] with column perm so attention's
//      PV A-fragment (kappa-fused tile pair) is one contiguous 16B read:
//      c' = (s&~31) | g*8 | tsel*4 | q   for s = (s>>5)*32 + tsel*16 + g*4 + q
__global__ __launch_bounds__(256) void qkv_gemm_k(
    const u16* __restrict__ hsb, const u16* __restrict__ wt,
    const float* __restrict__ bq, const float* __restrict__ bk, const float* __restrict__ bv,
    u16* __restrict__ Qo, u16* __restrict__ Ko, u16* __restrict__ Vto) {
  __shared__ u16 t1[128 * 64];
  __shared__ u16 t2[128 * 64];
  const int tid = threadIdx.x;
  const int w = tid >> 6, l = tid & 63, g = l >> 4, lm = l & 15;

  // XCD-aware bijective swizzle (nwg = 24*64 = 1536, 1536 % 8 == 0, q = 192)
  int lin = blockIdx.y * 24 + blockIdx.x;
  lin = (lin & 7) * 192 + (lin >> 3);
  const int bx = lin % 24, by = lin / 24;

  const int nbase = bx * 128;               // 0..3071 over {q,k,v}
  const int wi = nbase >> 10;               // 0=q 1=k 2=v
  const int nloc0 = nbase & 1023;
  const int mbase = by * 128;
  const bool swapped = (wi < 2);
  const u16* T1g = swapped ? (wt + wi * 1048576 + nloc0 * 1024) : (hsb + mbase * 1024);
  const u16* T2g = swapped ? (hsb + mbase * 1024) : (wt + 2 * 1048576 + nloc0 * 1024);

  f32x4 acc[4][4];
#pragma unroll
  for (int i = 0; i < 4; ++i)
#pragma unroll
    for (int j = 0; j < 4; ++j)
#pragma unroll
      for (int r = 0; r < 4; ++r) acc[i][j][r] = 0.f;

  const int r1w = (w >> 1) * 64;
  const int r2w = (w & 1) * 64;

  for (int kb = 0; kb < 1024; kb += 64) {
    __syncthreads();
#pragma unroll
    for (int p = 0; p < 4; ++p) {
      int idx = p * 256 + tid;
      int r = idx >> 3, c = idx & 7;
      int sc = (c ^ (r & 7)) << 3;           // pre-swizzled global column
      gld16(T1g + r * 1024 + kb + sc, t1 + idx * 8);
      gld16(T2g + r * 1024 + kb + sc, t2 + idx * 8);
    }
    __syncthreads();
#pragma unroll
    for (int ks = 0; ks < 2; ++ks) {
      bf16x8 fa[4], fb[4];
#pragma unroll
      for (int i = 0; i < 4; ++i) {
        int ra = r1w + i * 16 + lm;
        fa[i] = *(const bf16x8*)(t1 + ra * 64 + (((g + 4 * ks) ^ (ra & 7)) << 3));
        int rb = r2w + i * 16 + lm;
        fb[i] = *(const bf16x8*)(t2 + rb * 64 + (((g + 4 * ks) ^ (rb & 7)) << 3));
      }
      __builtin_amdgcn_s_setprio(1);
#pragma unroll
      for (int i = 0; i < 4; ++i)
#pragma unroll
        for (int j = 0; j < 4; ++j)
          acc[i][j] = __builtin_amdgcn_mfma_f32_16x16x32_bf16(fa[i], fb[j], acc[i][j], 0, 0, 0);
      __builtin_amdgcn_s_setprio(0);
    }
  }

  if (swapped) {
    u16* O = (wi == 0) ? Qo : Ko;
    const float* bias = (wi == 0) ? bq : bk;
#pragma unroll
    for (int i = 0; i < 4; ++i) {
      int nl = nloc0 + r1w + i * 16 + g * 4;   // 4 consecutive n = d
      f32x4 bv4 = *(const f32x4*)(bias + nl);
      int d = nl & 63, h = nl >> 6;
#pragma unroll
      for (int j = 0; j < 4; ++j) {
        int m = mbase + r2w + j * 16 + lm;
        int bb = m >> 11, s = m & 2047;
        f32x4 v = acc[i][j];
        ushort4 o = { f2b(v[0] + bv4[0]), f2b(v[1] + bv4[1]),
                      f2b(v[2] + bv4[2]), f2b(v[3] + bv4[3]) };
        *(ushort4*)(O + ((size_t)(bb * 16 + h) * 2048 + s) * 64 + d) = o;
      }
    }
  } else {
#pragma unroll
    for (int j = 0; j < 4; ++j) {
      int nl = nloc0 + r2w + j * 16 + lm;
      float bias = bv[nl];
      int d = nl & 63, h = nl >> 6;
#pragma unroll
      for (int i = 0; i < 4; ++i) {
        int m = mbase + r1w + i * 16 + g * 4;  // 4 consecutive m = s
        int bb = m >> 11, s = m & 2047;
        // PV-ready column permutation (4-aligned, q=0..3 stays contiguous)
        int cp = (s & ~31) | (((s >> 2) & 3) << 3) | (((s >> 4) & 1) << 2);
        f32x4 v = acc[i][j];
        ushort4 o = { f2b(v[0] + bias), f2b(v[1] + bias),
                      f2b(v[2] + bias), f2b(v[3] + bias) };
        *(ushort4*)(Vto + ((size_t)(bb * 16 + h) * 64 + d) * 2048 + cp) = o;
      }
    }
  }
}

// ---------------- kernel 4: flash attention ----------------
// 8 waves x 16 q-rows = 128 q/block. Swapped QK^T (St[sk][sq]); log2-domain
// online softmax with defer-max (THR=8); PV via kappa-fused tile pairs with
// V pre-permuted so the A-frag is one ds_read_b128.
__global__ __launch_bounds__(512) void attn_k(
    const u16* __restrict__ Qg, const u16* __restrict__ Kg, const u16* __restrict__ Vtg,
    const float* __restrict__ maskg, float* __restrict__ outp) {
  __shared__ u16 kt[128 * 64];   // [sk 128][d 64], content XOR'd at source
  __shared__ u16 vt[64 * 128];   // [d 64][c' 128], content XOR'd at source
  __shared__ float mk[128];
  const int tid = threadIdx.x;
  const int w = tid >> 6, l = tid & 63, g = l >> 4, lm = l & 15;

  // XCD swizzle: nwg = 16*64 = 1024 (1024 % 8 == 0) -> chunks of 128 share bh
  int bid = blockIdx.y * 16 + blockIdx.x;
  bid = (bid & 7) * 128 + (bid >> 3);
  const int bx = bid & 15, bh = bid >> 4;
  const int b = bh >> 4, h = bh & 15;
  const int q0 = bx * 128 + w * 16;
  const u16* Qb = Qg + ((size_t)bh * 2048 + q0) * 64;
  const u16* Kb = Kg + (size_t)bh * 2048 * 64;
  const u16* Vb = Vtg + (size_t)bh * 64 * 2048;
  const float* mb = maskg + b * 2048;

  bf16x8 qf0 = *(const bf16x8*)(Qb + lm * 64 + g * 8);
  bf16x8 qf1 = *(const bf16x8*)(Qb + lm * 64 + 32 + g * 8);

  f32x4 ctx[4];
#pragma unroll
  for (int dt = 0; dt < 4; ++dt)
#pragma unroll
    for (int r = 0; r < 4; ++r) ctx[dt][r] = 0.f;
  float mrun = -3.0e38f, lrun = 0.f;
  const float QS = 0.125f * LOG2E;

  for (int kv = 0; kv < 2048; kv += 128) {
    __syncthreads();
#pragma unroll
    for (int p = 0; p < 2; ++p) {
      int idx = p * 512 + tid;
      int rk = idx >> 3, ck = idx & 7;       // K tile: 128 x 64
      gld16(Kb + (size_t)(kv + rk) * 64 + ((ck ^ (rk & 7)) << 3), kt + idx * 8);
      int rv = idx >> 4, cv = idx & 15;      // Vt tile: 64 x 128
      gld16(Vb + (size_t)rv * 2048 + kv + ((cv ^ (rv & 7)) << 3), vt + idx * 8);
    }
    if (tid < 128) mk[tid] = mb[kv + tid] * LOG2E;
    __syncthreads();

    f32x4 st[8];
#pragma unroll
    for (int t = 0; t < 8; ++t)
#pragma unroll
      for (int r = 0; r < 4; ++r) st[t][r] = 0.f;

    __builtin_amdgcn_s_setprio(1);
#pragma unroll
    for (int ks = 0; ks < 2; ++ks) {
      bf16x8 qf = ks ? qf1 : qf0;
#pragma unroll
      for (int t = 0; t < 8; ++t) {
        int r = t * 16 + lm;
        bf16x8 kf = *(const bf16x8*)(kt + r * 64 + (((g + 4 * ks) ^ (r & 7)) << 3));
        st[t] = __builtin_amdgcn_mfma_f32_16x16x32_bf16(kf, qf, st[t], 0, 0, 0);
      }
    }
    __builtin_amdgcn_s_setprio(0);

    // scale+mask in log2 domain, running column max
    float tmax = -3.0e38f;
#pragma unroll
    for (int t = 0; t < 8; ++t) {
      f32x4 mv = *(const f32x4*)(mk + t * 16 + g * 4);
#pragma unroll
      for (int r = 0; r < 4; ++r) st[t][r] = fmaf(st[t][r], QS, mv[r]);
      tmax = fmaxf(tmax, fmaxf(fmaxf(st[t][0], st[t][1]), fmaxf(st[t][2], st[t][3])));
    }
    tmax = fmaxf(tmax, __shfl_xor(tmax, 16));
    tmax = fmaxf(tmax, __shfl_xor(tmax, 32));

    // defer-max (T13): only rescale when max grew past THR=8 (P <= 2^8, bf16-safe)
    if (!__all(tmax <= mrun + 8.0f)) {
      float mnew = fmaxf(mrun, tmax);
      float corr = exp2a(mrun - mnew);       // first tile: 2^(-inf) = 0
      lrun *= corr;
#pragma unroll
      for (int dt = 0; dt < 4; ++dt)
#pragma unroll
        for (int r = 0; r < 4; ++r) ctx[dt][r] *= corr;
      mrun = mnew;
    }

    int pt[8][2];
    float lsum = 0.f;
#pragma unroll
    for (int t = 0; t < 8; ++t) {
      float p0 = exp2a(st[t][0] - mrun);
      float p1 = exp2a(st[t][1] - mrun);
      float p2 = exp2a(st[t][2] - mrun);
      float p3 = exp2a(st[t][3] - mrun);
      lsum += (p0 + p1) + (p2 + p3);
      pt[t][0] = cvtpk(p0, p1);
      pt[t][1] = cvtpk(p2, p3);
    }
    lsum += __shfl_xor(lsum, 16);
    lsum += __shfl_xor(lsum, 32);
    lrun += lsum;

    // PV: tile pair (2tp, 2tp+1) fused into one K=32 mfma; A-frag is a single
    // contiguous 16B read thanks to the V column permutation.
    __builtin_amdgcn_s_setprio(1);
#pragma unroll
    for (int tp = 0; tp < 4; ++tp) {
      i32x4 pbi = { pt[2 * tp][0], pt[2 * tp][1], pt[2 * tp + 1][0], pt[2 * tp + 1][1] };
      bf16x8 pb = __builtin_bit_cast(bf16x8, pbi);
#pragma unroll
      for (int dt = 0; dt < 4; ++dt) {
        int r = dt * 16 + lm;
        bf16x8 va = *(const bf16x8*)(vt + r * 128 + (((tp * 4 + g) ^ (r & 7)) << 3));
        ctx[dt] = __builtin_amdgcn_mfma_f32_16x16x32_bf16(va, pb, ctx[dt], 0, 0, 0);
      }
    }
    __builtin_amdgcn_s_setprio(0);
  }

  float inv = 1.f / lrun;
  int sq = q0 + lm;
  float* ob = outp + ((size_t)(b * 2048 + sq)) * 1024 + h * 64;
#pragma unroll
  for (int dt = 0; dt < 4; ++dt) {
    f32x4 o;
#pragma unroll
    for (int r = 0; r < 4; ++r) o[r] = ctx[dt][r] * inv;
    *(f32x4*)(ob + dt * 16 + g * 4) = o;
  }
}

extern "C" void kernel_launch(void* const* d_in, const int* in_sizes, int n_in,
                              void* d_out, int out_size, void* d_ws, size_t ws_size,
                              hipStream_t stream) {
  const float* hs   = (const float*)d_in[0];
  const float* mask = (const float*)d_in[1];
  const float* Wq   = (const float*)d_in[2];
  const float* bq   = (const float*)d_in[3];
  const float* Wk   = (const float*)d_in[4];
  const float* bk   = (const float*)d_in[5];
  const float* Wv   = (const float*)d_in[6];
  const float* bv   = (const float*)d_in[7];
  float* out = (float*)d_out;

  char* ws = (char*)d_ws;
  u16* hsb = (u16*)(ws);                          // 16 MB: hs bf16 [8192][1024]
  u16* wt  = (u16*)(ws + (16u << 20));            //  6 MB: Wt bf16 [3][1024][1024]
  u16* Qb  = (u16*)(ws + (24u << 20));            // 16 MB: Q  [B][H][S][64]
  u16* Kb  = (u16*)(ws + (40u << 20));            // 16 MB: K  [B][H][S][64]
  u16* Vtb = (u16*)(ws + (56u << 20));            // 16 MB: Vt_perm [B][H][64][2048]

  cvt_hs_k<<<dim3(8192), dim3(256), 0, stream>>>(hs, hsb, 8388608);
  twk<<<dim3(16, 16, 3), dim3(256), 0, stream>>>(Wq, Wk, Wv, wt);
  qkv_gemm_k<<<dim3(24, 64), dim3(256), 0, stream>>>(hsb, wt, bq, bk, bv, Qb, Kb, Vtb);
  attn_k<<<dim3(16, 64), dim3(512), 0, stream>>>(Qb, Kb, Vtb, mask, out);
}